// Round 3
// baseline (418.273 us; speedup 1.0000x reference)
//
#include <hip/hip_runtime.h>
#include <math.h>

// Codebook argmin via split-bf16 MFMA: B=16, K=512, C=512, H=W=64.
// cross = xh*ch + xh*cl + xl*ch  (3x v_mfma_f32_32x32x16_bf16), error ~1.5e-4.
// R3: K-SPLIT. Each block does 256 clusters x 64 pixels -> acc[2][2] = 64
// AGPRs (was 128), __launch_bounds__(256,3) -> target 3 waves/SIMD. 2048
// blocks (pixel-group x k-half). Per-pixel (best,sec,k) written to ws; a
// combine kernel merges the two halves, flags near-ties (gap < MARGIN) and
// runs the fp64 recheck (moved out of the hot kernel).
// Counted-vmcnt 2-phase pipeline kept: stage(4 gload_lds)+xload(4) issued
// before compute; x-loads stay in flight across the barrier.

#define NK   512
#define NC   512
#define NHW  4096
#define NPX  65536            // 16 * 4096 pixels
#define MARGIN 0.02f

typedef unsigned short u16;
typedef __attribute__((ext_vector_type(8)))  short  short8;
typedef __attribute__((ext_vector_type(8)))  unsigned short ushort8;
typedef __attribute__((ext_vector_type(16))) float  f32x16;

__device__ __forceinline__ u16 f2bf(float f) {
    unsigned u = __builtin_bit_cast(unsigned, f);
    u += 0x7FFFu + ((u >> 16) & 1u);          // round-to-nearest-even bf16
    return (u16)(u >> 16);
}
__device__ __forceinline__ float bf2f(u16 h) {
    unsigned u = ((unsigned)h) << 16;
    return __builtin_bit_cast(float, u);
}

// Pack cluster centers into MFMA A-operand fragment order (hi & lo planes),
// grouped by k-half, and compute 0.5*c_sq.
// wcc layout: [chunk 32][half 2][unit 16][lane 64][8 bf16];
// unit u<8 -> hi of local m-tile u, u>=8 -> lo of local m-tile u-8.
__global__ __launch_bounds__(64) void prep_pack(const float* __restrict__ cc,
                                                u16* __restrict__ wcc,
                                                float* __restrict__ shalf) {
    const int k    = blockIdx.x;
    const int lane = threadIdx.x;      // 64 j-groups of 8 channels
    const int c0   = lane * 8;
    const float* row = cc + (size_t)k * NC + c0;
    ushort8 hi, lo;
    float sum = 0.f;
    #pragma unroll
    for (int i = 0; i < 8; ++i) {
        float v = row[i];
        sum = fmaf(v, v, sum);
        u16 h = f2bf(v);
        hi[i] = h;
        lo[i] = f2bf(v - bf2f(h));
    }
    const int ch  = c0 >> 4;           // 16-channel chunk
    const int kh  = (c0 >> 3) & 1;     // which 8-chan half of the chunk
    const int mtg = k >> 5;            // global m-tile 0..15
    const int h   = mtg >> 3;          // k-half
    const int mtl = mtg & 7;           // local m-tile 0..7
    const int ls  = (k & 31) + 32 * kh;
    *(ushort8*)(wcc + (((size_t)(ch * 2 + h) * 16 + mtl    ) * 64 + ls) * 8) = hi;
    *(ushort8*)(wcc + (((size_t)(ch * 2 + h) * 16 + 8 + mtl) * 64 + ls) * 8) = lo;
    #pragma unroll
    for (int off = 32; off > 0; off >>= 1) sum += __shfl_down(sum, off, 64);
    if (lane == 0) shalf[k] = 0.5f * sum;
}

__global__ __launch_bounds__(256, 3) void codebook_mfma(
        const float* __restrict__ x,
        const u16* __restrict__ wcc,
        const float* __restrict__ shalf,
        float* __restrict__ cbv,          // [2][NPX] best v per half
        float* __restrict__ csv,          // [2][NPX] second v per half
        int*   __restrict__ ckk)          // [2][NPX] best k (global) per half
{
    __shared__ __align__(16) u16 cs0[16 * 512];   // 16KB cluster frags, buf 0
    __shared__ __align__(16) u16 cs1[16 * 512];   // 16KB cluster frags, buf 1
    __shared__ __align__(16) u16 xs0[4 * 512];    // 4KB x frags, buf 0
    __shared__ __align__(16) u16 xs1[4 * 512];    // 4KB x frags, buf 1
    __shared__ float sh_s[256];

    const int tid  = threadIdx.x;
    const int w    = tid >> 6;
    const int lane = tid & 63;

    const int h   = blockIdx.x & 1;               // k-half
    const int gp0 = (blockIdx.x >> 1) * 64;       // pixel-group base
    const float* xb = x + (size_t)(gp0 >> 12) * (NC * NHW) + (gp0 & (NHW - 1));

    sh_s[tid] = shalf[h * 256 + tid];

    f32x16 acc[2][2] = {};

    // x staging assignment: pixel p, chunk-half kh, j-quarter jq (4 channels)
    const int p   = tid & 63;
    const int xkh = w & 1;
    const int jq  = w >> 1;
    const int xoff_hi = ((0 * 2 + (p >> 5)) * 64 + ((p & 31) + 32 * xkh)) * 8 + jq * 4;
    const int xoff_lo = xoff_hi + 2 * 512;
    const float* xp = xb + (size_t)(xkh * 8 + jq * 4) * NHW + p;

    float fxa[4], fxb[4];                        // 2-deep x prefetch registers

    auto xload = [&](float* fx, int ch) {
        const float* xc = xp + (size_t)ch * 16 * NHW;
        fx[0] = xc[0];
        fx[1] = xc[NHW];
        fx[2] = xc[2 * NHW];
        fx[3] = xc[3 * NHW];
    };
    auto xwrite = [&](const float* fx, u16* xs) {
        u16 h0 = f2bf(fx[0]), h1 = f2bf(fx[1]), h2 = f2bf(fx[2]), h3 = f2bf(fx[3]);
        u16 l0 = f2bf(fx[0] - bf2f(h0)), l1 = f2bf(fx[1] - bf2f(h1));
        u16 l2 = f2bf(fx[2] - bf2f(h2)), l3 = f2bf(fx[3] - bf2f(h3));
        uint2 hv = make_uint2((unsigned)h0 | ((unsigned)h1 << 16),
                              (unsigned)h2 | ((unsigned)h3 << 16));
        uint2 lv = make_uint2((unsigned)l0 | ((unsigned)l1 << 16),
                              (unsigned)l2 | ((unsigned)l3 << 16));
        *(uint2*)&xs[xoff_hi] = hv;
        *(uint2*)&xs[xoff_lo] = lv;
    };
    // 16 units x 1KB = 16KB per chunk; 4 gload_lds per wave.
    auto stage_cs = [&](int ch, u16* dst) {
        #pragma unroll
        for (int i = 0; i < 4; ++i) {
            const int u = w * 4 + i;
            const u16* g = wcc + (((size_t)(ch * 2 + h) * 16 + u) * 64 + lane) * 8;
            __builtin_amdgcn_global_load_lds(
                (const __attribute__((address_space(1))) void*)g,
                (__attribute__((address_space(3))) void*)(dst + u * 512),
                16, 0, 0);
        }
    };
    auto compute = [&](const u16* csb, const u16* xsb) {
        short8 bh[2], bl[2];
        #pragma unroll
        for (int nt = 0; nt < 2; ++nt) {
            bh[nt] = *(const short8*)&xsb[((0 * 2 + nt) * 64 + lane) * 8];
            bl[nt] = *(const short8*)&xsb[((1 * 2 + nt) * 64 + lane) * 8];
        }
        #pragma unroll
        for (int mtl2 = 0; mtl2 < 2; ++mtl2) {
            const int gm = w * 2 + mtl2;          // local m-tile 0..7
            short8 ah = *(const short8*)&csb[((size_t)gm * 64 + lane) * 8];
            short8 al = *(const short8*)&csb[((size_t)(8 + gm) * 64 + lane) * 8];
            #pragma unroll
            for (int nt = 0; nt < 2; ++nt) {
                acc[mtl2][nt] = __builtin_amdgcn_mfma_f32_32x32x16_bf16(ah, bh[nt], acc[mtl2][nt], 0, 0, 0);
                acc[mtl2][nt] = __builtin_amdgcn_mfma_f32_32x32x16_bf16(al, bh[nt], acc[mtl2][nt], 0, 0, 0);
                acc[mtl2][nt] = __builtin_amdgcn_mfma_f32_32x32x16_bf16(ah, bl[nt], acc[mtl2][nt], 0, 0, 0);
            }
        }
    };

    // vmcnt accounting (issue order pinned by sched_barrier(0)):
    // steady entry: fx_cur 4 outstanding. +4 stage -> 8; +4 xload -> 12.
    // vmcnt(8): fx_cur drained. vmcnt(4): stage drained, fx_nxt stays in
    // flight ACROSS the barrier.
    auto phase = [&](int t, u16* cs_cur, u16* cs_nxt, u16* xs_cur, u16* xs_nxt,
                     float* fx_cur, float* fx_nxt) {
        stage_cs(t + 1, cs_nxt);
        __builtin_amdgcn_sched_barrier(0);
        xload(fx_nxt, t + 2);
        asm volatile("s_waitcnt vmcnt(8)" ::: "memory");
        xwrite(fx_cur, xs_nxt);
        compute(cs_cur, xs_cur);
        asm volatile("s_waitcnt vmcnt(4) lgkmcnt(0)" ::: "memory");
        __builtin_amdgcn_s_barrier();
        __builtin_amdgcn_sched_barrier(0);
    };

    // ---- prologue ----
    asm volatile("s_waitcnt vmcnt(0)" ::: "memory");  // drain sh_s load
    xload(fxa, 0);                                    // 4 (oldest)
    __builtin_amdgcn_sched_barrier(0);
    stage_cs(0, cs0);                                 // +4 -> 8
    __builtin_amdgcn_sched_barrier(0);
    xload(fxb, 1);                                    // +4 -> 12
    asm volatile("s_waitcnt vmcnt(8)" ::: "memory");  // fxa ready
    xwrite(fxa, xs0);
    asm volatile("s_waitcnt vmcnt(4) lgkmcnt(0)" ::: "memory"); // cs0 done
    __builtin_amdgcn_s_barrier();
    __builtin_amdgcn_sched_barrier(0);

    // ---- main loop: chunks 0..29 ----
    for (int t = 0; t < 30; t += 2) {
        phase(t,     cs0, cs1, xs0, xs1, fxb, fxa);
        phase(t + 1, cs1, cs0, xs1, xs0, fxa, fxb);
    }

    // ---- tail: chunk 30 computes, chunk 31 staged ----
    stage_cs(31, cs1);                                // fxb(4) + 4 -> 8
    asm volatile("s_waitcnt vmcnt(4)" ::: "memory");  // fxb ready
    xwrite(fxb, xs1);
    compute(cs0, xs0);
    asm volatile("s_waitcnt vmcnt(0) lgkmcnt(0)" ::: "memory");
    __builtin_amdgcn_s_barrier();
    __builtin_amdgcn_sched_barrier(0);
    compute(cs1, xs1);
    __syncthreads();

    // ---- epilogue: per-half top-2 -> ws (overlays cs0) ----
    float* cand_v = (float*)cs0;             // 2KB
    float* cand_s = cand_v + 512;            // 2KB
    int*   cand_k = (int*)(cand_s + 512);    // 2KB

    const int qb = lane >> 5;
    #pragma unroll
    for (int nt = 0; nt < 2; ++nt) {
        float best = -INFINITY, sec = -INFINITY;
        int bk = 0;
        #pragma unroll
        for (int mtl2 = 0; mtl2 < 2; ++mtl2) {
            const int kbase = w * 64 + mtl2 * 32 + 4 * qb;
            #pragma unroll
            for (int reg = 0; reg < 16; ++reg) {
                const int k = kbase + (reg & 3) + 8 * (reg >> 2);  // ascending
                const float v = acc[mtl2][nt][reg] - sh_s[k];
                if (v > best) { sec = best; best = v; bk = k; }
                else if (v > sec) sec = v;
            }
        }
        const int pc   = nt * 32 + (lane & 31);
        const int slot = w * 2 + qb;
        cand_v[pc * 8 + slot] = best;
        cand_s[pc * 8 + slot] = sec;
        cand_k[pc * 8 + slot] = bk;
    }
    __syncthreads();

    if (tid < 64) {
        float best = -INFINITY, sec = -INFINITY;
        int bk = 1 << 30;
        #pragma unroll
        for (int s = 0; s < 8; ++s) {
            float v  = cand_v[tid * 8 + s];
            float v2 = cand_s[tid * 8 + s];
            int  kk  = cand_k[tid * 8 + s];
            if (v > best || (v == best && kk < bk)) {
                sec = fmaxf(sec, best);
                best = v; bk = kk;
            } else sec = fmaxf(sec, v);
            sec = fmaxf(sec, v2);
        }
        const int gpx = gp0 + tid;
        cbv[h * NPX + gpx] = best;
        csv[h * NPX + gpx] = sec;
        ckk[h * NPX + gpx] = h * 256 + bk;
    }
}

// Merge the two k-halves per pixel; flag near-ties; fp64 recheck the rare
// flagged pixels block-cooperatively.
__global__ __launch_bounds__(256) void combine(
        const float* __restrict__ x,
        const float* __restrict__ cc,
        const float* __restrict__ cbv,
        const float* __restrict__ csv,
        const int*   __restrict__ ckk,
        int* __restrict__ out)
{
    __shared__ int   fcnt;
    __shared__ int   fpx[256];
    __shared__ float xcol[NC];
    __shared__ double dvv[256];
    __shared__ int    dii[256];

    const int tid = threadIdx.x;
    const int px  = blockIdx.x * 256 + tid;

    const float b0 = cbv[px],        b1 = cbv[NPX + px];
    const float s0 = csv[px],        s1 = csv[NPX + px];
    const int   k0 = ckk[px],        k1 = ckk[NPX + px];

    float best, sec; int bk;
    if (b0 >= b1) { best = b0; bk = k0; sec = fmaxf(s0, b1); }
    else          { best = b1; bk = k1; sec = fmaxf(s1, b0); }

    if (tid == 0) fcnt = 0;
    __syncthreads();
    out[px] = bk;
    if (best - sec < MARGIN) { int i = atomicAdd(&fcnt, 1); fpx[i] = tid; }
    __syncthreads();

    const int n = fcnt;
    for (int i = 0; i < n; ++i) {
        const int gpx = blockIdx.x * 256 + fpx[i];
        const float* xb = x + (size_t)(gpx >> 12) * (NC * NHW);
        const int hw = gpx & (NHW - 1);
        for (int c = tid; c < NC; c += 256)
            xcol[c] = xb[(size_t)c * NHW + hw];
        __syncthreads();
        double bd = 1e300;
        int bkk = 1 << 30;
        #pragma unroll
        for (int r = 0; r < 2; ++r) {
            const int k = tid + r * 256;
            const float4* crow = (const float4*)(cc + (size_t)k * NC);
            const float4* xc4  = (const float4*)xcol;
            double d = 0.0;
            for (int c4 = 0; c4 < NC / 4; ++c4) {
                float4 cv = crow[c4], xv = xc4[c4];
                double d0 = (double)xv.x - (double)cv.x;
                double d1 = (double)xv.y - (double)cv.y;
                double d2 = (double)xv.z - (double)cv.z;
                double d3 = (double)xv.w - (double)cv.w;
                d = fma(d0, d0, d); d = fma(d1, d1, d);
                d = fma(d2, d2, d); d = fma(d3, d3, d);
            }
            if (d < bd || (d == bd && k < bkk)) { bd = d; bkk = k; }
        }
        dvv[tid] = bd; dii[tid] = bkk;
        __syncthreads();
        for (int srd = 128; srd > 0; srd >>= 1) {
            if (tid < srd) {
                double ov = dvv[tid + srd]; int oi = dii[tid + srd];
                if (ov < dvv[tid] || (ov == dvv[tid] && oi < dii[tid])) {
                    dvv[tid] = ov; dii[tid] = oi;
                }
            }
            __syncthreads();
        }
        if (tid == 0) out[gpx] = dii[0];
        __syncthreads();
    }
}

extern "C" void kernel_launch(void* const* d_in, const int* in_sizes, int n_in,
                              void* d_out, int out_size, void* d_ws, size_t ws_size,
                              hipStream_t stream) {
    const float* x  = (const float*)d_in[0];   // (16, 512, 64, 64) f32
    const float* cc = (const float*)d_in[1];   // (1, 512, 512, 1, 1) f32 -> [k][c]
    int* out = (int*)d_out;                    // (16, 1, 64, 64) int32

    float* shalf = (float*)d_ws;                     // 512 floats (2KB)
    u16*   wcc   = (u16*)(shalf + NK);               // 1MB frag-ordered hi/lo bf16
    float* cbv   = (float*)(wcc + 32 * 2 * 16 * 64 * 8);  // 2*NPX floats
    float* csv   = cbv + 2 * NPX;                    // 2*NPX floats
    int*   ckk   = (int*)(csv + 2 * NPX);            // 2*NPX ints

    prep_pack<<<NK, 64, 0, stream>>>(cc, wcc, shalf);
    codebook_mfma<<<(NPX / 64) * 2, 256, 0, stream>>>(x, wcc, shalf, cbv, csv, ckk);
    combine<<<NPX / 256, 256, 0, stream>>>(x, cc, cbv, csv, ckk, out);
}

// Round 4
// 307.080 us; speedup vs baseline: 1.3621x; 1.3621x over previous
//
#include <hip/hip_runtime.h>
#include <math.h>

// Codebook argmin via split-bf16 MFMA: B=16, K=512, C=512, H=W=64.
// cross = xh*ch + xh*cl + xl*ch  (3x v_mfma_f32_32x32x16_bf16), error ~1.5e-4.
// R3: K-SPLIT. Each block does 256 clusters x 64 pixels -> acc[2][2] = 64
// AGPRs, __launch_bounds__(256,3) -> 3 waves/SIMD (237 -> ~140 us).
// R4: the R3 combine kernel serialized the fp64 near-tie recheck (153 us at
// 1.7% occupancy). Split into: merge (per-pixel half-merge + global compact
// of flagged pixels) and recheck (grid-stride, ONE BLOCK PER FLAGGED PIXEL,
// 2-way split fp64 accumulators). prep_pack zeroes the flag counter.

#define NK   512
#define NC   512
#define NHW  4096
#define NPX  65536            // 16 * 4096 pixels
#define MARGIN 0.02f

typedef unsigned short u16;
typedef __attribute__((ext_vector_type(8)))  short  short8;
typedef __attribute__((ext_vector_type(8)))  unsigned short ushort8;
typedef __attribute__((ext_vector_type(16))) float  f32x16;

__device__ __forceinline__ u16 f2bf(float f) {
    unsigned u = __builtin_bit_cast(unsigned, f);
    u += 0x7FFFu + ((u >> 16) & 1u);          // round-to-nearest-even bf16
    return (u16)(u >> 16);
}
__device__ __forceinline__ float bf2f(u16 h) {
    unsigned u = ((unsigned)h) << 16;
    return __builtin_bit_cast(float, u);
}

// Pack cluster centers into MFMA A-operand fragment order (hi & lo planes),
// grouped by k-half, and compute 0.5*c_sq. Also zeroes the flag counter.
// wcc layout: [chunk 32][half 2][unit 16][lane 64][8 bf16];
// unit u<8 -> hi of local m-tile u, u>=8 -> lo of local m-tile u-8.
__global__ __launch_bounds__(64) void prep_pack(const float* __restrict__ cc,
                                                u16* __restrict__ wcc,
                                                float* __restrict__ shalf,
                                                int* __restrict__ gcnt) {
    const int k    = blockIdx.x;
    const int lane = threadIdx.x;      // 64 j-groups of 8 channels
    if (k == 0 && lane == 0) gcnt[0] = 0;
    const int c0   = lane * 8;
    const float* row = cc + (size_t)k * NC + c0;
    ushort8 hi, lo;
    float sum = 0.f;
    #pragma unroll
    for (int i = 0; i < 8; ++i) {
        float v = row[i];
        sum = fmaf(v, v, sum);
        u16 h = f2bf(v);
        hi[i] = h;
        lo[i] = f2bf(v - bf2f(h));
    }
    const int ch  = c0 >> 4;           // 16-channel chunk
    const int kh  = (c0 >> 3) & 1;     // which 8-chan half of the chunk
    const int mtg = k >> 5;            // global m-tile 0..15
    const int h   = mtg >> 3;          // k-half
    const int mtl = mtg & 7;           // local m-tile 0..7
    const int ls  = (k & 31) + 32 * kh;
    *(ushort8*)(wcc + (((size_t)(ch * 2 + h) * 16 + mtl    ) * 64 + ls) * 8) = hi;
    *(ushort8*)(wcc + (((size_t)(ch * 2 + h) * 16 + 8 + mtl) * 64 + ls) * 8) = lo;
    #pragma unroll
    for (int off = 32; off > 0; off >>= 1) sum += __shfl_down(sum, off, 64);
    if (lane == 0) shalf[k] = 0.5f * sum;
}

__global__ __launch_bounds__(256, 3) void codebook_mfma(
        const float* __restrict__ x,
        const u16* __restrict__ wcc,
        const float* __restrict__ shalf,
        float* __restrict__ cbv,          // [2][NPX] best v per half
        float* __restrict__ csv,          // [2][NPX] second v per half
        int*   __restrict__ ckk)          // [2][NPX] best k (global) per half
{
    __shared__ __align__(16) u16 cs0[16 * 512];   // 16KB cluster frags, buf 0
    __shared__ __align__(16) u16 cs1[16 * 512];   // 16KB cluster frags, buf 1
    __shared__ __align__(16) u16 xs0[4 * 512];    // 4KB x frags, buf 0
    __shared__ __align__(16) u16 xs1[4 * 512];    // 4KB x frags, buf 1
    __shared__ float sh_s[256];

    const int tid  = threadIdx.x;
    const int w    = tid >> 6;
    const int lane = tid & 63;

    const int h   = blockIdx.x & 1;               // k-half
    const int gp0 = (blockIdx.x >> 1) * 64;       // pixel-group base
    const float* xb = x + (size_t)(gp0 >> 12) * (NC * NHW) + (gp0 & (NHW - 1));

    sh_s[tid] = shalf[h * 256 + tid];

    f32x16 acc[2][2] = {};

    // x staging assignment: pixel p, chunk-half kh, j-quarter jq (4 channels)
    const int p   = tid & 63;
    const int xkh = w & 1;
    const int jq  = w >> 1;
    const int xoff_hi = ((0 * 2 + (p >> 5)) * 64 + ((p & 31) + 32 * xkh)) * 8 + jq * 4;
    const int xoff_lo = xoff_hi + 2 * 512;
    const float* xp = xb + (size_t)(xkh * 8 + jq * 4) * NHW + p;

    float fxa[4], fxb[4];                        // 2-deep x prefetch registers

    auto xload = [&](float* fx, int ch) {
        const float* xc = xp + (size_t)ch * 16 * NHW;
        fx[0] = xc[0];
        fx[1] = xc[NHW];
        fx[2] = xc[2 * NHW];
        fx[3] = xc[3 * NHW];
    };
    auto xwrite = [&](const float* fx, u16* xs) {
        u16 h0 = f2bf(fx[0]), h1 = f2bf(fx[1]), h2 = f2bf(fx[2]), h3 = f2bf(fx[3]);
        u16 l0 = f2bf(fx[0] - bf2f(h0)), l1 = f2bf(fx[1] - bf2f(h1));
        u16 l2 = f2bf(fx[2] - bf2f(h2)), l3 = f2bf(fx[3] - bf2f(h3));
        uint2 hv = make_uint2((unsigned)h0 | ((unsigned)h1 << 16),
                              (unsigned)h2 | ((unsigned)h3 << 16));
        uint2 lv = make_uint2((unsigned)l0 | ((unsigned)l1 << 16),
                              (unsigned)l2 | ((unsigned)l3 << 16));
        *(uint2*)&xs[xoff_hi] = hv;
        *(uint2*)&xs[xoff_lo] = lv;
    };
    // 16 units x 1KB = 16KB per chunk; 4 gload_lds per wave.
    auto stage_cs = [&](int ch, u16* dst) {
        #pragma unroll
        for (int i = 0; i < 4; ++i) {
            const int u = w * 4 + i;
            const u16* g = wcc + (((size_t)(ch * 2 + h) * 16 + u) * 64 + lane) * 8;
            __builtin_amdgcn_global_load_lds(
                (const __attribute__((address_space(1))) void*)g,
                (__attribute__((address_space(3))) void*)(dst + u * 512),
                16, 0, 0);
        }
    };
    auto compute = [&](const u16* csb, const u16* xsb) {
        short8 bh[2], bl[2];
        #pragma unroll
        for (int nt = 0; nt < 2; ++nt) {
            bh[nt] = *(const short8*)&xsb[((0 * 2 + nt) * 64 + lane) * 8];
            bl[nt] = *(const short8*)&xsb[((1 * 2 + nt) * 64 + lane) * 8];
        }
        #pragma unroll
        for (int mtl2 = 0; mtl2 < 2; ++mtl2) {
            const int gm = w * 2 + mtl2;          // local m-tile 0..7
            short8 ah = *(const short8*)&csb[((size_t)gm * 64 + lane) * 8];
            short8 al = *(const short8*)&csb[((size_t)(8 + gm) * 64 + lane) * 8];
            #pragma unroll
            for (int nt = 0; nt < 2; ++nt) {
                acc[mtl2][nt] = __builtin_amdgcn_mfma_f32_32x32x16_bf16(ah, bh[nt], acc[mtl2][nt], 0, 0, 0);
                acc[mtl2][nt] = __builtin_amdgcn_mfma_f32_32x32x16_bf16(al, bh[nt], acc[mtl2][nt], 0, 0, 0);
                acc[mtl2][nt] = __builtin_amdgcn_mfma_f32_32x32x16_bf16(ah, bl[nt], acc[mtl2][nt], 0, 0, 0);
            }
        }
    };

    // vmcnt accounting (issue order pinned by sched_barrier(0)):
    // steady entry: fx_cur 4 outstanding. +4 stage -> 8; +4 xload -> 12.
    // vmcnt(8): fx_cur drained. vmcnt(4): stage drained, fx_nxt stays in
    // flight ACROSS the barrier.
    auto phase = [&](int t, u16* cs_cur, u16* cs_nxt, u16* xs_cur, u16* xs_nxt,
                     float* fx_cur, float* fx_nxt) {
        stage_cs(t + 1, cs_nxt);
        __builtin_amdgcn_sched_barrier(0);
        xload(fx_nxt, t + 2);
        asm volatile("s_waitcnt vmcnt(8)" ::: "memory");
        xwrite(fx_cur, xs_nxt);
        compute(cs_cur, xs_cur);
        asm volatile("s_waitcnt vmcnt(4) lgkmcnt(0)" ::: "memory");
        __builtin_amdgcn_s_barrier();
        __builtin_amdgcn_sched_barrier(0);
    };

    // ---- prologue ----
    asm volatile("s_waitcnt vmcnt(0)" ::: "memory");  // drain sh_s load
    xload(fxa, 0);                                    // 4 (oldest)
    __builtin_amdgcn_sched_barrier(0);
    stage_cs(0, cs0);                                 // +4 -> 8
    __builtin_amdgcn_sched_barrier(0);
    xload(fxb, 1);                                    // +4 -> 12
    asm volatile("s_waitcnt vmcnt(8)" ::: "memory");  // fxa ready
    xwrite(fxa, xs0);
    asm volatile("s_waitcnt vmcnt(4) lgkmcnt(0)" ::: "memory"); // cs0 done
    __builtin_amdgcn_s_barrier();
    __builtin_amdgcn_sched_barrier(0);

    // ---- main loop: chunks 0..29 ----
    for (int t = 0; t < 30; t += 2) {
        phase(t,     cs0, cs1, xs0, xs1, fxb, fxa);
        phase(t + 1, cs1, cs0, xs1, xs0, fxa, fxb);
    }

    // ---- tail: chunk 30 computes, chunk 31 staged ----
    stage_cs(31, cs1);                                // fxb(4) + 4 -> 8
    asm volatile("s_waitcnt vmcnt(4)" ::: "memory");  // fxb ready
    xwrite(fxb, xs1);
    compute(cs0, xs0);
    asm volatile("s_waitcnt vmcnt(0) lgkmcnt(0)" ::: "memory");
    __builtin_amdgcn_s_barrier();
    __builtin_amdgcn_sched_barrier(0);
    compute(cs1, xs1);
    __syncthreads();

    // ---- epilogue: per-half top-2 -> ws (overlays cs0) ----
    float* cand_v = (float*)cs0;             // 2KB
    float* cand_s = cand_v + 512;            // 2KB
    int*   cand_k = (int*)(cand_s + 512);    // 2KB

    const int qb = lane >> 5;
    #pragma unroll
    for (int nt = 0; nt < 2; ++nt) {
        float best = -INFINITY, sec = -INFINITY;
        int bk = 0;
        #pragma unroll
        for (int mtl2 = 0; mtl2 < 2; ++mtl2) {
            const int kbase = w * 64 + mtl2 * 32 + 4 * qb;
            #pragma unroll
            for (int reg = 0; reg < 16; ++reg) {
                const int k = kbase + (reg & 3) + 8 * (reg >> 2);  // ascending
                const float v = acc[mtl2][nt][reg] - sh_s[k];
                if (v > best) { sec = best; best = v; bk = k; }
                else if (v > sec) sec = v;
            }
        }
        const int pc   = nt * 32 + (lane & 31);
        const int slot = w * 2 + qb;
        cand_v[pc * 8 + slot] = best;
        cand_s[pc * 8 + slot] = sec;
        cand_k[pc * 8 + slot] = bk;
    }
    __syncthreads();

    if (tid < 64) {
        float best = -INFINITY, sec = -INFINITY;
        int bk = 1 << 30;
        #pragma unroll
        for (int s = 0; s < 8; ++s) {
            float v  = cand_v[tid * 8 + s];
            float v2 = cand_s[tid * 8 + s];
            int  kk  = cand_k[tid * 8 + s];
            if (v > best || (v == best && kk < bk)) {
                sec = fmaxf(sec, best);
                best = v; bk = kk;
            } else sec = fmaxf(sec, v);
            sec = fmaxf(sec, v2);
        }
        const int gpx = gp0 + tid;
        cbv[h * NPX + gpx] = best;
        csv[h * NPX + gpx] = sec;
        ckk[h * NPX + gpx] = h * 256 + bk;
    }
}

// Per-pixel merge of the two k-halves; writes out; compacts near-tie pixels
// into a global list for the recheck kernel.
__global__ __launch_bounds__(256) void merge(
        const float* __restrict__ cbv,
        const float* __restrict__ csv,
        const int*   __restrict__ ckk,
        int* __restrict__ out,
        int* __restrict__ glist,
        int* __restrict__ gcnt)
{
    const int px = blockIdx.x * 256 + threadIdx.x;

    const float b0 = cbv[px],        b1 = cbv[NPX + px];
    const float s0 = csv[px],        s1 = csv[NPX + px];
    const int   k0 = ckk[px],        k1 = ckk[NPX + px];

    float best, sec; int bk;
    if (b0 >= b1) { best = b0; bk = k0; sec = fmaxf(s0, b1); }
    else          { best = b1; bk = k1; sec = fmaxf(s1, b0); }

    out[px] = bk;
    if (best - sec < MARGIN) {
        int i = atomicAdd(gcnt, 1);
        glist[i] = px;
    }
}

// One BLOCK per flagged pixel (grid-stride over the compacted list):
// cooperative fp64 exact distance over all 512 clusters.
__global__ __launch_bounds__(256) void recheck(
        const float* __restrict__ x,
        const float* __restrict__ cc,
        const int*   __restrict__ glist,
        const int*   __restrict__ gcnt,
        int* __restrict__ out)
{
    __shared__ float  xcol[NC];
    __shared__ double dvv[256];
    __shared__ int    dii[256];

    const int tid = threadIdx.x;
    const int n   = gcnt[0];

    for (int idx = blockIdx.x; idx < n; idx += gridDim.x) {
        const int gpx = glist[idx];
        const float* xb = x + (size_t)(gpx >> 12) * (NC * NHW);
        const int hw = gpx & (NHW - 1);
        for (int c = tid; c < NC; c += 256)
            xcol[c] = xb[(size_t)c * NHW + hw];
        __syncthreads();
        double bd = 1e300;
        int bkk = 1 << 30;
        #pragma unroll
        for (int r = 0; r < 2; ++r) {
            const int k = tid + r * 256;
            const float4* crow = (const float4*)(cc + (size_t)k * NC);
            const float4* xc4  = (const float4*)xcol;
            double da = 0.0, db = 0.0;           // 2-way split: halve chain latency
            for (int c4 = 0; c4 < NC / 4; ++c4) {
                float4 cv = crow[c4], xv = xc4[c4];
                double d0 = (double)xv.x - (double)cv.x;
                double d1 = (double)xv.y - (double)cv.y;
                double d2 = (double)xv.z - (double)cv.z;
                double d3 = (double)xv.w - (double)cv.w;
                da = fma(d0, d0, da); db = fma(d1, d1, db);
                da = fma(d2, d2, da); db = fma(d3, d3, db);
            }
            double d = da + db;
            if (d < bd || (d == bd && k < bkk)) { bd = d; bkk = k; }
        }
        dvv[tid] = bd; dii[tid] = bkk;
        __syncthreads();
        for (int srd = 128; srd > 0; srd >>= 1) {
            if (tid < srd) {
                double ov = dvv[tid + srd]; int oi = dii[tid + srd];
                if (ov < dvv[tid] || (ov == dvv[tid] && oi < dii[tid])) {
                    dvv[tid] = ov; dii[tid] = oi;
                }
            }
            __syncthreads();
        }
        if (tid == 0) out[gpx] = dii[0];
        __syncthreads();
    }
}

extern "C" void kernel_launch(void* const* d_in, const int* in_sizes, int n_in,
                              void* d_out, int out_size, void* d_ws, size_t ws_size,
                              hipStream_t stream) {
    const float* x  = (const float*)d_in[0];   // (16, 512, 64, 64) f32
    const float* cc = (const float*)d_in[1];   // (1, 512, 512, 1, 1) f32 -> [k][c]
    int* out = (int*)d_out;                    // (16, 1, 64, 64) int32

    float* shalf = (float*)d_ws;                          // 512 floats (2KB)
    u16*   wcc   = (u16*)(shalf + NK);                    // 1MB frag-ordered
    float* cbv   = (float*)(wcc + 32 * 2 * 16 * 64 * 8);  // 2*NPX floats
    float* csv   = cbv + 2 * NPX;                         // 2*NPX floats
    int*   ckk   = (int*)(csv + 2 * NPX);                 // 2*NPX ints
    int*   glist = ckk + 2 * NPX;                         // NPX ints
    int*   gcnt  = glist + NPX;                           // 1 int

    prep_pack<<<NK, 64, 0, stream>>>(cc, wcc, shalf, gcnt);
    codebook_mfma<<<(NPX / 64) * 2, 256, 0, stream>>>(x, wcc, shalf, cbv, csv, ckk);
    merge<<<NPX / 256, 256, 0, stream>>>(cbv, csv, ckk, out, glist, gcnt);
    recheck<<<512, 256, 0, stream>>>(x, cc, glist, gcnt, out);
}